// Round 3
// baseline (343.099 us; speedup 1.0000x reference)
//
#include <hip/hip_runtime.h>
#include <stdint.h>

#define DEVINL __device__ __forceinline__

typedef short bf16x8 __attribute__((ext_vector_type(8)));
typedef float f32x4  __attribute__((ext_vector_type(4)));

// ---------- bf16 helpers (RNE) ----------
DEVINL uint16_t f2bf(float f) {
    uint32_t u = __builtin_bit_cast(uint32_t, f);
    uint32_t r = u + 0x7fffu + ((u >> 16) & 1u);
    return (uint16_t)(r >> 16);
}

DEVINL f32x4 mfma16x16x32(bf16x8 a, bf16x8 b, f32x4 c) {
    return __builtin_amdgcn_mfma_f32_16x16x32_bf16(a, b, c, 0, 0, 0);
}

// ---------- ws layout (bytes) ----------
// Bfrag1: GEMM1 B pre-fragmented [13 step][4 w][2 kk][4 ni][64 lane][8] bf16
//         = 212992 elems = 425984 B @ 0        (k>=784 zero-padded)
// Bfrag2: GEMM2 B [8 k0s][2 ni][64][8]  = 16384 B @ 425984
// Bfrag3: clsf L1 B [8 ni][64][8]       =  8192 B @ 442368
// Bfrag4: clsf L2 B [4 k0s][64][8]      =  4096 B @ 450560  (n>=10 zero)
#define WS_BF1 0
#define WS_BF2 425984
#define WS_BF3 442368
#define WS_BF4 450560

// ================= prep: weights -> bf16 MFMA-fragment layouts =================
__global__ __launch_bounds__(256) void prep_weights(
    const float* __restrict__ We1, const float* __restrict__ We2,
    const float* __restrict__ W1,  const float* __restrict__ W2,
    uint16_t* __restrict__ Bf1, uint16_t* __restrict__ Bf2,
    uint16_t* __restrict__ Bf3, uint16_t* __restrict__ Bf4) {
    int tid = blockIdx.x * 256 + threadIdx.x;
    if (tid < 212992) {            // GEMM1: n = w*64+ni*16+(lane&15), k = step*64+kk*32+(lane>>4)*8+e
        int e    = tid & 7;
        int lane = (tid >> 3) & 63;
        int ni   = (tid >> 9) & 3;
        int kk   = (tid >> 11) & 1;
        int w    = (tid >> 12) & 3;
        int step = tid >> 14;
        int n = w * 64 + ni * 16 + (lane & 15);
        int k = step * 64 + kk * 32 + (lane >> 4) * 8 + e;
        Bf1[tid] = (k < 784) ? f2bf(We1[k * 256 + n]) : (uint16_t)0;
        return;
    }
    int t2 = tid - 212992;
    if (t2 < 8192) {               // GEMM2: n = ni*16+(lane&15), k = k0s*32+(lane>>4)*8+e
        int e    = t2 & 7;
        int lane = (t2 >> 3) & 63;
        int ni   = (t2 >> 9) & 1;
        int k0s  = t2 >> 10;
        int n = ni * 16 + (lane & 15);
        int k = k0s * 32 + (lane >> 4) * 8 + e;
        Bf2[t2] = f2bf(We2[k * 32 + n]);
        return;
    }
    int t3 = t2 - 8192;
    if (t3 < 4096) {               // clsf L1: n = ni*16+(lane&15), k = (lane>>4)*8+e
        int e    = t3 & 7;
        int lane = (t3 >> 3) & 63;
        int ni   = t3 >> 9;
        int n = ni * 16 + (lane & 15);
        int k = (lane >> 4) * 8 + e;
        Bf3[t3] = f2bf(W1[k * 128 + n]);
        return;
    }
    int t4 = t3 - 4096;
    if (t4 < 2048) {               // clsf L2: n = lane&15, k = k0s*32+(lane>>4)*8+e
        int e    = t4 & 7;
        int lane = (t4 >> 3) & 63;
        int k0s  = t4 >> 9;
        int n = lane & 15;
        int k = k0s * 32 + (lane >> 4) * 8 + e;
        Bf4[t4] = (n < 10) ? f2bf(W2[k * 10 + n]) : (uint16_t)0;
        return;
    }
}

// ================= quantum circuit (fixed angles, fully unrolled) =================
DEVINL void apply_rx(float* sr, float* si, int bit, float c, float s) {
    #pragma unroll
    for (int i = 0; i < 16; i++) {
        if (!(i & bit)) {
            int j = i | bit;
            float r0 = sr[i], i0 = si[i], r1 = sr[j], i1 = si[j];
            sr[i] = c * r0 + s * i1;  si[i] = c * i0 - s * r1;
            sr[j] = c * r1 + s * i0;  si[j] = c * i1 - s * r0;
        }
    }
}
DEVINL void apply_ry(float* sr, float* si, int bit, float c, float s) {
    #pragma unroll
    for (int i = 0; i < 16; i++) {
        if (!(i & bit)) {
            int j = i | bit;
            float r0 = sr[i], i0 = si[i], r1 = sr[j], i1 = si[j];
            sr[i] = c * r0 - s * r1;  si[i] = c * i0 - s * i1;
            sr[j] = s * r0 + c * r1;  si[j] = s * i0 + c * i1;
        }
    }
}
DEVINL void apply_cnot(float* sr, float* si, int cb, int tb) {
    #pragma unroll
    for (int i = 0; i < 16; i++) {
        if ((i & cb) && !(i & tb)) {
            int j = i | tb;
            float tr = sr[i]; sr[i] = sr[j]; sr[j] = tr;
            float ti = si[i]; si[i] = si[j]; si[j] = ti;
        }
    }
}
DEVINL void circuit(float* sr, float* si) {
    const float C1 = 0.99875026039496628f, S1 = 0.04997916927067833f;  // rx(0.1)
    const float C2 = 0.99500416527802582f, S2 = 0.09983341664682815f;  // ry(0.2)
    const float C3 = 0.98877107793604227f, S3 = 0.14943813247359922f;  // rx(0.3)
    const float C4 = 0.98006657784124163f, S4 = 0.19866933079506122f;  // ry(0.4)
    #pragma unroll
    for (int q = 0; q < 4; q++) {
        int bit = 8 >> q;
        apply_rx(sr, si, bit, C1, S1);
        apply_ry(sr, si, bit, C2, S2);
    }
    apply_cnot(sr, si, 8, 4);
    apply_cnot(sr, si, 4, 2);
    apply_cnot(sr, si, 2, 1);
    #pragma unroll
    for (int q = 0; q < 4; q++) {
        int bit = 8 >> q;
        apply_rx(sr, si, bit, C3, S3);
        apply_ry(sr, si, bit, C4, S4);
    }
}

// ---------------- K-loop building blocks ----------------
DEVINL void pack_A(const float4* va, uint16_t* Als, int ar, int ach0, int ach1) {
    union { uint4 u4; uint16_t us[8]; } p0, p1;
    p0.us[0] = f2bf(va[0].x); p0.us[1] = f2bf(va[0].y);
    p0.us[2] = f2bf(va[0].z); p0.us[3] = f2bf(va[0].w);
    p0.us[4] = f2bf(va[1].x); p0.us[5] = f2bf(va[1].y);
    p0.us[6] = f2bf(va[1].z); p0.us[7] = f2bf(va[1].w);
    p1.us[0] = f2bf(va[2].x); p1.us[1] = f2bf(va[2].y);
    p1.us[2] = f2bf(va[2].z); p1.us[3] = f2bf(va[2].w);
    p1.us[4] = f2bf(va[3].x); p1.us[5] = f2bf(va[3].y);
    p1.us[6] = f2bf(va[3].z); p1.us[7] = f2bf(va[3].w);
    *(uint4*)&Als[ar * 64 + ach0 * 8] = p0.u4;
    *(uint4*)&Als[ar * 64 + ach1 * 8] = p1.u4;
}

DEVINL void load_va(float4* va, const float* __restrict__ xrow, int k0, int ac) {
    // Always 4 loads; clamp keeps addresses in-bounds. Garbage cols >=784 are
    // finite x floats and multiply zeroed B columns -> no contribution.
    #pragma unroll
    for (int j = 0; j < 4; j++) {
        int c = k0 + ac + j * 4;
        c = (c <= 780) ? c : 780;
        va[j] = *(const float4*)(xrow + c);
    }
}

// compute one K-step: A fragments from (swizzled) LDS, B fragments DIRECT from
// global pre-fragmented layout (contiguous 1 KB per load instruction, L2-hot).
DEVINL void compute_tile(const uint16_t* Als, const uint16_t* __restrict__ Bf,
                         f32x4 (&acc)[4][4], int l, int lm, int lq) {
    #pragma unroll
    for (int kk = 0; kk < 2; kk++) {
        bf16x8 afr[4], bfr[4];
        #pragma unroll
        for (int ni = 0; ni < 4; ni++)
            bfr[ni] = *(const bf16x8*)&Bf[(kk * 4 + ni) * 512 + l * 8];
        #pragma unroll
        for (int mi = 0; mi < 4; mi++) {
            int ch = (kk * 4 + lq) ^ (lm & 7);
            afr[mi] = *(const bf16x8*)&Als[(mi * 16 + lm) * 64 + ch * 8];
        }
        __builtin_amdgcn_s_setprio(1);
        #pragma unroll
        for (int mi = 0; mi < 4; mi++)
            #pragma unroll
            for (int ni = 0; ni < 4; ni++)
                acc[mi][ni] = mfma16x16x32(afr[mi], bfr[ni], acc[mi][ni]);
        __builtin_amdgcn_s_setprio(0);
    }
}

// ================= fused kernel =================
// 1024 blocks x 256 thr (4 waves); 64 rows/block; N-tile 256 = full h width.
// K-loop: NO global_load_lds, NO vmcnt drains. B fragments stream from L2 via
// coalesced global loads (compiler pipelines them freely across raw barriers).
// Only the 8 KB A-tile goes through LDS (2-buffer), guarded by ONE raw
// s_barrier + lgkmcnt(0) per step. x prefetched 2 steps ahead in registers.
// LDS arena 34816 B (Htile-governed) -> 4 blocks/CU, 16 waves/CU.
__global__ __launch_bounds__(256, 4) void fused_kernel(
    const float* __restrict__ x, const uint16_t* __restrict__ Bf1,
    const float* __restrict__ be1,
    const uint16_t* __restrict__ Bf2, const float* __restrict__ be2,
    const uint16_t* __restrict__ Bf3, const float* __restrict__ b1,
    const uint16_t* __restrict__ Bf4, const float* __restrict__ b2,
    float* __restrict__ out) {
    __shared__ __align__(16) char smem[34816];
    uint16_t* Abuf[2] = { (uint16_t*)smem, (uint16_t*)(smem + 8192) };  // [64][64] each
    // phase 2: Htile [64][272] bf16 = 34816 B (whole arena)
    uint16_t* Htile = (uint16_t*)smem;
    // phase 3 (tail): enc/feat/a1
    float*    encls  = (float*)smem;               // [64][33] f32 = 8448 B
    uint16_t* featls = (uint16_t*)(smem + 8448);   // [64][40] bf16 = 5120 B
    uint16_t* a1ls   = (uint16_t*)(smem + 13568);  // [64][136] bf16 = 17408 B

    const int t = threadIdx.x;
    const int rowbase = blockIdx.x * 64;
    const int w  = t >> 6;     // wave 0..3 -> n-block w*64 in GEMM1; rows w*16.. in tail
    const int l  = t & 63;
    const int lm = l & 15;
    const int lq = l >> 4;

    f32x4 acc[4][4] = {};      // [mi][ni] -> rows mi*16.., cols w*64+ni*16..

    // A staging: thread t owns row ar, 16 f32 at col ac (two swizzled 16B chunks)
    const int ar = t >> 2;
    const int ac = (t & 3) * 16;
    const float* xrow = x + (size_t)(rowbase + ar) * 784;
    const int ach0 = ((t & 3) * 2)     ^ (ar & 7);
    const int ach1 = ((t & 3) * 2 + 1) ^ (ar & 7);

    float4 v[2][4];

    // ---- prologue ----
    load_va(v[0], xrow, 0,   ac);                  // data 0
    load_va(v[1], xrow, 64,  ac);                  // data 1
    pack_A(v[0], Abuf[0], ar, ach0, ach1);         // tile 0 -> buf0
    load_va(v[0], xrow, 128, ac);                  // data 2 (2 steps ahead)
    asm volatile("s_waitcnt lgkmcnt(0)" ::: "memory");
    __builtin_amdgcn_s_barrier();
    __builtin_amdgcn_sched_barrier(0x7F);          // block DS motion only

    #pragma unroll
    for (int it = 0; it < 13; ++it) {
        if (it < 12)
            pack_A(v[(it + 1) & 1], Abuf[(it + 1) & 1], ar, ach0, ach1);
        if (it < 10)
            load_va(v[(it + 1) & 1], xrow, (it + 3) * 64, ac);  // keep 2 batches in flight
        compute_tile(Abuf[it & 1], Bf1 + (size_t)(it * 4 + w) * 4096, acc, l, lm, lq);
        asm volatile("s_waitcnt lgkmcnt(0)" ::: "memory");  // A writes + frag reads done
        __builtin_amdgcn_s_barrier();
        __builtin_amdgcn_sched_barrier(0x7F);               // DS ops may not cross; VMEM may
    }

    __syncthreads();   // full drain; arena becomes Htile

    // ---- GEMM1 epilogue: relu(+bias) -> Htile bf16 [64][272] ----
    #pragma unroll
    for (int ni = 0; ni < 4; ni++) {
        int n = w * 64 + ni * 16 + lm;
        float bias = be1[n];
        #pragma unroll
        for (int mi = 0; mi < 4; mi++) {
            #pragma unroll
            for (int i = 0; i < 4; i++) {
                int r = mi * 16 + lq * 4 + i;
                float v2 = acc[mi][ni][i] + bias;
                v2 = v2 > 0.f ? v2 : 0.f;
                Htile[r * 272 + n] = f2bf(v2);
            }
        }
    }
    __syncthreads();   // Htile complete

    // ---- GEMM2: enc_pre = h @ We2, K=256; B frags direct from global (L2-hot) ----
    f32x4 acc2[2] = {};
    #pragma unroll
    for (int k0 = 0; k0 < 256; k0 += 32) {
        bf16x8 af = *(const bf16x8*)&Htile[(w * 16 + lm) * 272 + k0 + lq * 8];
        #pragma unroll
        for (int ni = 0; ni < 2; ni++) {
            bf16x8 bf = *(const bf16x8*)&Bf2[((k0 >> 5) * 2 + ni) * 512 + l * 8];
            acc2[ni] = mfma16x16x32(af, bf, acc2[ni]);
        }
    }
    __syncthreads();   // all waves' Htile reads done; arena becomes enc/feat/a1

    // ---- enc = tanh(acc + be2) -> LDS ----
    #pragma unroll
    for (int ni = 0; ni < 2; ni++) {
        int col = ni * 16 + lm;
        float bias = be2[col];
        #pragma unroll
        for (int i = 0; i < 4; i++) {
            int r = w * 16 + lq * 4 + i;
            encls[r * 33 + col] = tanhf(acc2[ni][i] + bias);
        }
    }
    __syncthreads();   // enc visible cross-wave

    // ---- per-row: normalize + quantum circuit -> feat bf16 ----
    if (t < 64) {
        float e[32];
        #pragma unroll
        for (int j = 0; j < 32; j++) e[j] = encls[t * 33 + j];
        float s = 0.f;
        #pragma unroll
        for (int j = 0; j < 32; j++) s += e[j] * e[j];
        float inv = 1.0f / sqrtf(s);
        float sr[16], si[16];
        #pragma unroll
        for (int i = 0; i < 16; i++) { sr[i] = e[i] * inv; si[i] = e[16 + i] * inv; }
        circuit(sr, si);
        #pragma unroll
        for (int i = 0; i < 16; i++) {
            featls[t * 40 + i]      = f2bf(sr[i]);
            featls[t * 40 + 16 + i] = f2bf(si[i]);
        }
    }
    __syncthreads();   // feat visible cross-wave

    // ---- classifier L1: a1 = relu(feat @ W1 + b1), K=32 ----
    f32x4 acc3[8] = {};
    {
        bf16x8 af = *(const bf16x8*)&featls[(w * 16 + lm) * 40 + lq * 8];
        #pragma unroll
        for (int ni = 0; ni < 8; ni++) {
            bf16x8 bf = *(const bf16x8*)&Bf3[ni * 512 + l * 8];
            acc3[ni] = mfma16x16x32(af, bf, acc3[ni]);
        }
    }
    #pragma unroll
    for (int ni = 0; ni < 8; ni++) {
        int col = ni * 16 + lm;
        float bias = b1[col];
        #pragma unroll
        for (int i = 0; i < 4; i++) {
            int r = w * 16 + lq * 4 + i;   // same wave writes & reads these rows
            float v2 = acc3[ni][i] + bias;
            v2 = v2 > 0.f ? v2 : 0.f;
            a1ls[r * 136 + col] = f2bf(v2);
        }
    }
    // no barrier: wave w wrote exactly the a1 rows it reads below

    // ---- classifier L2: out = a1 @ W2 + b2, K=128, N=16 (10 real) ----
    f32x4 acc4 = {};
    #pragma unroll
    for (int k0 = 0; k0 < 128; k0 += 32) {
        bf16x8 af = *(const bf16x8*)&a1ls[(w * 16 + lm) * 136 + k0 + lq * 8];
        bf16x8 bf = *(const bf16x8*)&Bf4[(k0 >> 5) * 512 + l * 8];
        acc4 = mfma16x16x32(af, bf, acc4);
    }
    if (lm < 10) {
        float bias = b2[lm];
        #pragma unroll
        for (int i = 0; i < 4; i++) {
            int r = rowbase + w * 16 + lq * 4 + i;
            out[(size_t)r * 10 + lm] = acc4[i] + bias;
        }
    }
}

extern "C" void kernel_launch(void* const* d_in, const int* in_sizes, int n_in,
                              void* d_out, int out_size, void* d_ws, size_t ws_size,
                              hipStream_t stream) {
    const float* x   = (const float*)d_in[0];
    const float* We1 = (const float*)d_in[1];
    const float* be1 = (const float*)d_in[2];
    const float* We2 = (const float*)d_in[3];
    const float* be2 = (const float*)d_in[4];
    const float* W1  = (const float*)d_in[5];
    const float* b1  = (const float*)d_in[6];
    const float* W2  = (const float*)d_in[7];
    const float* b2  = (const float*)d_in[8];
    float* out = (float*)d_out;

    char* ws = (char*)d_ws;
    uint16_t* Bf1 = (uint16_t*)(ws + WS_BF1);
    uint16_t* Bf2 = (uint16_t*)(ws + WS_BF2);
    uint16_t* Bf3 = (uint16_t*)(ws + WS_BF3);
    uint16_t* Bf4 = (uint16_t*)(ws + WS_BF4);

    // 212992 + 8192 + 4096 + 2048 = 227328 threads = 888 blocks
    hipLaunchKernelGGL(prep_weights, dim3(888), dim3(256), 0, stream,
                       We1, We2, W1, W2, Bf1, Bf2, Bf3, Bf4);
    hipLaunchKernelGGL(fused_kernel, dim3(1024), dim3(256), 0, stream,
                       x, Bf1, be1, Bf2, be2, Bf3, b1, Bf4, b2, out);
}